// Round 9
// baseline (224.232 us; speedup 1.0000x reference)
//
#include <hip/hip_runtime.h>

// ScRRAMBLe capsule layer — R12: asm-pinned 16-deep Wi pipeline.
//   A) xr[ch,c,k,m] = sum_{ij in ch} Ci[ij,c,k] * x[ij,m]   (R1 structure)
//   B) y[c,j,l]     = sum_{k,m} Wi[c,j,k,l,m] * xr[c,k,m]
//
// R11 post-mortem: lb(256,6) was a no-op — transform was ALREADY at 32
// waves/CU (2048 blocks / 256 CU = 8 blocks/CU, VGPR 36-58, no LDS).
// Transform invariant ~72us (~1.9 TB/s) across reg-hoist / batch / GLDS
// variants. Little's law: 32 waves x 1KB outstanding >> 9.2KB BW-delay
// product -> should saturate. It doesn't => the scheduler rewrites EVERY
// source-level hoist into load-few/drain/consume (VGPR=36 with wv[16]
// proves it). R12: inline-asm global_load_dwordx4 x16 with named f4
// outputs — regalloc MUST keep 64 dest VGPRs live, loads issue
// back-to-back; one s_waitcnt vmcnt(0) + sched_barrier(0) (rule #18),
// then FMAs. 16KB/wave truly in flight; 16 waves/CU -> 256KB/CU.
// Predicted: transform ~25us, total ~175us. If total ~221: depth
// exonerated -> next round surfaces transform counters via x2 repeat.

typedef float f4 __attribute__((ext_vector_type(4)));

#define NCH 4   // ij chunks; xr partials = NCH*512*256 floats = 2 MB in d_ws

// ---------------- Kernel A: routing einsum (R1 lineage, NCH=4) -------------
__global__ __launch_bounds__(256) void route_kernel(
    const float* __restrict__ x,
    const float* __restrict__ Ci,
    float* __restrict__ xr_part)
{
    const int iq  = blockIdx.x;
    const int c   = blockIdx.y;
    const int t   = threadIdx.x;
    const int il  = t >> 6;
    const int g   = (t >> 4) & 3;
    const int mq4 = t & 15;
    const int i   = (iq << 2) + il;

    const f4* __restrict__ Ci4 = (const f4*)Ci;
    const f4* __restrict__ x4  = (const f4*)x;

    __shared__ f4 part[1024];   // [g][il][r][mq4]

    f4 a0 = {0.f,0.f,0.f,0.f};
    f4 a1 = {0.f,0.f,0.f,0.f};
    f4 a2 = {0.f,0.f,0.f,0.f};
    f4 a3 = {0.f,0.f,0.f,0.f};

    const int ijpc = 2048 / NCH;      // 512
    const int sub  = ijpc >> 2;       // 128 per g-subgroup
    const int base = c * ijpc + g * sub;
    #pragma unroll 4
    for (int it = 0; it < sub; ++it) {
        const int ij = base + it;
        const f4 c4 = Ci4[ij * 512 + i];
        const f4 xv = x4[(ij << 4) + mq4];
        a0 += c4.x * xv;
        a1 += c4.y * xv;
        a2 += c4.z * xv;
        a3 += c4.w * xv;
    }

    const int pb = ((g << 2) + il) << 2;
    part[(pb + 0) * 16 + mq4] = a0;
    part[(pb + 1) * 16 + mq4] = a1;
    part[(pb + 2) * 16 + mq4] = a2;
    part[(pb + 3) * 16 + mq4] = a3;
    __syncthreads();

    const int il2 = t >> 6;
    const int r   = (t >> 4) & 3;
    const int mm  = t & 15;
    f4 s = {0.f,0.f,0.f,0.f};
    #pragma unroll
    for (int gg = 0; gg < 4; ++gg)
        s += part[(((gg << 2) + il2) * 4 + r) * 16 + mm];

    f4* __restrict__ xp4 = (f4*)xr_part;
    xp4[(c * 512 + (iq << 2) + il2) * 64 + r * 16 + mm] = s;
}

// ---------------- Kernel B: transform, asm-pinned 16-deep pipeline ---------
// grid 2048 = (i*4+j); block 256; wave w owns l in [w*16, w*16+16).
__global__ __launch_bounds__(256, 2) void transform_kernel(
    const float* __restrict__ Wi,
    const float* __restrict__ xr_part,
    float* __restrict__ y)
{
    const int b    = blockIdx.x;
    const int i    = b >> 2;
    const int t    = threadIdx.x;
    const int lane = t & 63;
    const int w    = t >> 6;
    const int lq   = lane >> 4;
    const int m16  = lane & 15;
    const int lw   = w << 4;

    const f4* __restrict__ xp4 = (const f4*)xr_part;

    // xr gather: NCH=4 -> 16 loads in two 8-deep batches (transient regs).
    f4 xr0, xr1, xr2, xr3;
    {
        f4 tmp[8];
        #pragma unroll
        for (int ch = 0; ch < 2; ++ch)
            #pragma unroll
            for (int k = 0; k < 4; ++k)
                tmp[(ch << 2) + k] =
                    xp4[(((ch << 9) + i) << 6) + (k << 4) + m16];
        xr0 = tmp[0] + tmp[4];
        xr1 = tmp[1] + tmp[5];
        xr2 = tmp[2] + tmp[6];
        xr3 = tmp[3] + tmp[7];
        #pragma unroll
        for (int ch = 0; ch < 2; ++ch)
            #pragma unroll
            for (int k = 0; k < 4; ++k)
                tmp[(ch << 2) + k] =
                    xp4[((((ch + 2) << 9) + i) << 6) + (k << 4) + m16];
        xr0 += tmp[0] + tmp[4];
        xr1 += tmp[1] + tmp[5];
        xr2 += tmp[2] + tmp[6];
        xr3 += tmp[3] + tmp[7];
    }

    // Wi: 16 asm-pinned loads, issue back-to-back, ONE drain, then consume.
    // element (c2,k): float offset = k*4096 + (lw + c2*4 + lq)*64 + m16*4
    const float* wp = Wi + ((size_t)b << 14);   // b * 16384 floats

    f4 wv0, wv1, wv2,  wv3,  wv4,  wv5,  wv6,  wv7;
    f4 wv8, wv9, wv10, wv11, wv12, wv13, wv14, wv15;

#define WLOAD(n, c2, k)                                                      \
    {                                                                        \
        const float* ap = wp + ((k) << 12)                                   \
                        + ((lw + ((c2) << 2) + lq) << 6) + (m16 << 2);       \
        asm volatile("global_load_dwordx4 %0, %1, off"                       \
                     : "=v"(wv##n) : "v"(ap));                               \
    }

    WLOAD(0, 0, 0)  WLOAD(1, 0, 1)  WLOAD(2, 0, 2)  WLOAD(3, 0, 3)
    WLOAD(4, 1, 0)  WLOAD(5, 1, 1)  WLOAD(6, 1, 2)  WLOAD(7, 1, 3)
    WLOAD(8, 2, 0)  WLOAD(9, 2, 1)  WLOAD(10, 2, 2) WLOAD(11, 2, 3)
    WLOAD(12, 3, 0) WLOAD(13, 3, 1) WLOAD(14, 3, 2) WLOAD(15, 3, 3)
#undef WLOAD

    asm volatile("s_waitcnt vmcnt(0)" ::: "memory");
    __builtin_amdgcn_sched_barrier(0);   // rule #18: no hoisting past the wait

#define CONSUME(c2, wa, wb, wc, wd)                                          \
    {                                                                        \
        f4 s = wa * xr0 + wb * xr1 + wc * xr2 + wd * xr3;                    \
        float p = s.x + s.y + s.z + s.w;                                     \
        p += __shfl_xor(p, 1);                                               \
        p += __shfl_xor(p, 2);                                               \
        p += __shfl_xor(p, 4);                                               \
        p += __shfl_xor(p, 8);                                               \
        if (m16 == 0) y[(b << 6) + lw + ((c2) << 2) + lq] = p;               \
    }

    CONSUME(0, wv0,  wv1,  wv2,  wv3)
    CONSUME(1, wv4,  wv5,  wv6,  wv7)
    CONSUME(2, wv8,  wv9,  wv10, wv11)
    CONSUME(3, wv12, wv13, wv14, wv15)
#undef CONSUME
}

extern "C" void kernel_launch(void* const* d_in, const int* in_sizes, int n_in,
                              void* d_out, int out_size, void* d_ws, size_t ws_size,
                              hipStream_t stream) {
    const float* x  = (const float*)d_in[0];   // 131072 floats
    const float* Ci = (const float*)d_in[1];   // 2048*512*4 floats (16 MB)
    const float* Wi = (const float*)d_in[2];   // 512*4*4*64*64 floats (134 MB)
    float* y  = (float*)d_out;                 // 512*4*64 floats
    float* xr = (float*)d_ws;                  // 2 MB partials

    route_kernel<<<dim3(128, NCH), 256, 0, stream>>>(x, Ci, xr);
    transform_kernel<<<2048, 256, 0, stream>>>(Wi, xr, y);
}